// Round 3
// baseline (1446.753 us; speedup 1.0000x reference)
//
#include <hip/hip_runtime.h>

#define DD 64
#define TILE_ROWS 64

__device__ __forceinline__ float fast_tanh(float x) {
    float e = __builtin_amdgcn_exp2f(x * 2.885390081777927f); // 2x * log2(e)
    return 1.0f - 2.0f * __builtin_amdgcn_rcpf(e + 1.0f);
}

// ---------------- CSR build ----------------

__global__ void __launch_bounds__(256) count_deg(
    const int* __restrict__ dst, int* __restrict__ deg, int E)
{
    int e = blockIdx.x * 256 + threadIdx.x;
    if (e < E) atomicAdd(&deg[dst[e]], 1);
}

// single block, 1024 threads: exclusive scan deg[N] -> off[N+1], cursor = off
__global__ void __launch_bounds__(1024) scan_kernel(
    const int* __restrict__ deg, int* __restrict__ off,
    int* __restrict__ cursor, int N)
{
    __shared__ int part[1024];
    int t = threadIdx.x;
    int per = (N + 1023) / 1024;
    int lo = t * per;
    int hi = lo + per; if (hi > N) hi = N;
    int s = 0;
    for (int i = lo; i < hi; ++i) s += deg[i];
    part[t] = s;
    __syncthreads();
    for (int d = 1; d < 1024; d <<= 1) {
        int v = 0;
        if (t >= d) v = part[t - d];
        __syncthreads();
        if (t >= d) part[t] += v;
        __syncthreads();
    }
    int run = (t == 0) ? 0 : part[t - 1];
    for (int i = lo; i < hi; ++i) {
        off[i] = run; cursor[i] = run;
        run += deg[i];
    }
    if (lo < N && hi == N) off[N] = run;
}

__global__ void __launch_bounds__(256) fill_eidx(
    const int* __restrict__ dst, int* __restrict__ cursor,
    int* __restrict__ eidx, int E)
{
    int e = blockIdx.x * 256 + threadIdx.x;
    if (e < E) {
        int slot = atomicAdd(&cursor[dst[e]], 1);
        eidx[slot] = e;
    }
}

// ---------------- compute kernels ----------------

// hm = h @ W(top 64x64) + b ; zero pooled (atomics accumulate into it)
__global__ void __launch_bounds__(256) node_transform(
    const float* __restrict__ h, const float* __restrict__ W,
    const float* __restrict__ b, float* __restrict__ hm,
    float* __restrict__ pooled, int N)
{
    int n = blockIdx.x * 256 + threadIdx.x;
    if (n >= N) return;
    float acc[DD];
    #pragma unroll
    for (int j = 0; j < DD; ++j) acc[j] = b[j];
    const float4* hrow = reinterpret_cast<const float4*>(h + (size_t)n * DD);
    #pragma unroll 1
    for (int kk = 0; kk < DD / 4; ++kk) {
        float4 a = hrow[kk];
        const float* Wr = W + kk * 4 * DD;   // uniform -> s_load
        #pragma unroll
        for (int j = 0; j < DD; ++j)
            acc[j] += a.x * Wr[j] + a.y * Wr[DD + j]
                    + a.z * Wr[2 * DD + j] + a.w * Wr[3 * DD + j];
    }
    float4* orow = reinterpret_cast<float4*>(hm + (size_t)n * DD);
    float4* prow = reinterpret_cast<float4*>(pooled + (size_t)n * DD);
    #pragma unroll
    for (int jj = 0; jj < DD / 4; ++jj) {
        orow[jj] = make_float4(acc[4*jj], acc[4*jj+1], acc[4*jj+2], acc[4*jj+3]);
        prow[jj] = make_float4(0.f, 0.f, 0.f, 0.f);
    }
}

// Fused: per CSR slot compute msg = tanh(ef[e]@W + hm[src]) and segment-sum
// into pooled via block-local LDS tile (edges sorted by dst).
__global__ void __launch_bounds__(256) fused_edge_gather(
    const float* __restrict__ ef, const float* __restrict__ hm,
    const int* __restrict__ src, const int* __restrict__ dst,
    const int* __restrict__ off, const int* __restrict__ eidx,
    const float* __restrict__ W, float* __restrict__ pooled,
    int E, int N)
{
    __shared__ float tile[TILE_ROWS][DD];   // 16 KiB
    int t  = threadIdx.x;
    int s0 = blockIdx.x * 256;
    int s1 = s0 + 256; if (s1 > E) s1 = E;
    int d_first = dst[eidx[s0]];            // same addr all threads -> broadcast

    #pragma unroll
    for (int i = 0; i < TILE_ROWS * DD / 256; ++i)
        ((float*)tile)[t + i * 256] = 0.0f;
    __syncthreads();

    int slot = s0 + t;
    if (slot < s1) {
        int e = eidx[slot];
        int s = src[e];
        int d = dst[e];
        float acc[DD];
        #pragma unroll
        for (int j = 0; j < DD; ++j) acc[j] = 0.0f;
        const float4* erow = reinterpret_cast<const float4*>(ef + (size_t)e * DD);
        #pragma unroll 1
        for (int kk = 0; kk < DD / 4; ++kk) {
            float4 a = erow[kk];
            const float* Wr = W + kk * 4 * DD;   // uniform -> s_load
            #pragma unroll
            for (int j = 0; j < DD; ++j)
                acc[j] += a.x * Wr[j] + a.y * Wr[DD + j]
                        + a.z * Wr[2 * DD + j] + a.w * Wr[3 * DD + j];
        }
        const float4* hrow = reinterpret_cast<const float4*>(hm + (size_t)s * DD);
        #pragma unroll
        for (int jj = 0; jj < DD / 4; ++jj) {
            float4 hv = hrow[jj];
            acc[4*jj+0] = fast_tanh(acc[4*jj+0] + hv.x);
            acc[4*jj+1] = fast_tanh(acc[4*jj+1] + hv.y);
            acc[4*jj+2] = fast_tanh(acc[4*jj+2] + hv.z);
            acc[4*jj+3] = fast_tanh(acc[4*jj+3] + hv.w);
        }
        int lidx = d - d_first;
        if (lidx < TILE_ROWS) {
            #pragma unroll
            for (int j = 0; j < DD; ++j)
                atomicAdd(&tile[lidx][j], acc[j]);       // ds_add_f32
        } else {
            // rare: block spans >64 nodes (degree-0 gaps) -> direct global
            float* prow = pooled + (size_t)d * DD;
            #pragma unroll
            for (int j = 0; j < DD; ++j)
                atomicAdd(prow + j, acc[j]);
        }
    }
    __syncthreads();

    // write-out: lane = channel, 4 row-phases; coalesced 256B stores
    int ch = t & 63;
    for (int r = t >> 6; r < TILE_ROWS; r += 4) {
        int n = d_first + r;
        if (n >= N) break;
        int lo = off[n], hi = off[n + 1];
        int clo = lo > s0 ? lo : s0;
        int chi = hi < s1 ? hi : s1;
        if (clo >= chi) continue;            // node untouched by this block
        float v = tile[r][ch];
        if (lo >= s0 && hi <= s1)
            pooled[(size_t)n * DD + ch] = v; // exclusively owned -> store
        else
            atomicAdd(pooled + (size_t)n * DD + ch, v);  // straddles blocks
    }
}

// fallback path: atomic scatter (round-0 kernel) if ws too small
__global__ void __launch_bounds__(256) edge_kernel_atomic(
    const float* __restrict__ ef, const float* __restrict__ hm,
    const int* __restrict__ src, const int* __restrict__ dst,
    const float* __restrict__ W, float* __restrict__ pooled, int E)
{
    int e = blockIdx.x * 256 + threadIdx.x;
    if (e >= E) return;
    int s = src[e];
    int d = dst[e];
    float acc[DD];
    #pragma unroll
    for (int j = 0; j < DD; ++j) acc[j] = 0.0f;
    const float4* erow = reinterpret_cast<const float4*>(ef + (size_t)e * DD);
    #pragma unroll 1
    for (int kk = 0; kk < DD / 4; ++kk) {
        float4 a = erow[kk];
        const float* Wr = W + kk * 4 * DD;
        #pragma unroll
        for (int j = 0; j < DD; ++j)
            acc[j] += a.x * Wr[j] + a.y * Wr[DD + j]
                    + a.z * Wr[2 * DD + j] + a.w * Wr[3 * DD + j];
    }
    const float4* hrow = reinterpret_cast<const float4*>(hm + (size_t)s * DD);
    float* prow = pooled + (size_t)d * DD;
    #pragma unroll
    for (int jj = 0; jj < DD / 4; ++jj) {
        float4 hv = hrow[jj];
        atomicAdd(prow + 4*jj + 0, fast_tanh(acc[4*jj+0] + hv.x));
        atomicAdd(prow + 4*jj + 1, fast_tanh(acc[4*jj+1] + hv.y));
        atomicAdd(prow + 4*jj + 2, fast_tanh(acc[4*jj+2] + hv.z));
        atomicAdd(prow + 4*jj + 3, fast_tanh(acc[4*jj+3] + hv.w));
    }
}

// h_new = tanh(h @ Wu[0:64] + pooled @ Wu[64:128] + bu)
__global__ void __launch_bounds__(256) update_kernel(
    const float* __restrict__ h, const float* __restrict__ pooled,
    const float* __restrict__ Wu, const float* __restrict__ bu,
    float* __restrict__ hout, int N)
{
    int n = blockIdx.x * 256 + threadIdx.x;
    if (n >= N) return;
    float acc[DD];
    #pragma unroll
    for (int j = 0; j < DD; ++j) acc[j] = bu[j];
    const float4* hrow = reinterpret_cast<const float4*>(h + (size_t)n * DD);
    #pragma unroll 1
    for (int kk = 0; kk < DD / 4; ++kk) {
        float4 a = hrow[kk];
        const float* Wr = Wu + kk * 4 * DD;
        #pragma unroll
        for (int j = 0; j < DD; ++j)
            acc[j] += a.x * Wr[j] + a.y * Wr[DD + j]
                    + a.z * Wr[2 * DD + j] + a.w * Wr[3 * DD + j];
    }
    const float4* prow = reinterpret_cast<const float4*>(pooled + (size_t)n * DD);
    #pragma unroll 1
    for (int kk = 0; kk < DD / 4; ++kk) {
        float4 a = prow[kk];
        const float* Wr = Wu + (DD + kk * 4) * DD;
        #pragma unroll
        for (int j = 0; j < DD; ++j)
            acc[j] += a.x * Wr[j] + a.y * Wr[DD + j]
                    + a.z * Wr[2 * DD + j] + a.w * Wr[3 * DD + j];
    }
    float4* orow = reinterpret_cast<float4*>(hout + (size_t)n * DD);
    #pragma unroll
    for (int jj = 0; jj < DD / 4; ++jj)
        orow[jj] = make_float4(fast_tanh(acc[4*jj]),   fast_tanh(acc[4*jj+1]),
                               fast_tanh(acc[4*jj+2]), fast_tanh(acc[4*jj+3]));
}

__global__ void __launch_bounds__(256) out_kernel(
    const float* __restrict__ h, const float* __restrict__ Wo,
    const float* __restrict__ bo, float* __restrict__ out, int N)
{
    int n = blockIdx.x * 256 + threadIdx.x;
    if (n >= N) return;
    const float4* hrow = reinterpret_cast<const float4*>(h + (size_t)n * DD);
    float acc = bo[0];
    #pragma unroll
    for (int kk = 0; kk < DD / 4; ++kk) {
        float4 a = hrow[kk];
        acc += a.x * Wo[4*kk] + a.y * Wo[4*kk+1] + a.z * Wo[4*kk+2] + a.w * Wo[4*kk+3];
    }
    out[n] = acc;
}

extern "C" void kernel_launch(void* const* d_in, const int* in_sizes, int n_in,
                              void* d_out, int out_size, void* d_ws, size_t ws_size,
                              hipStream_t stream) {
    const float* node = (const float*)d_in[0];
    const float* ef   = (const float*)d_in[1];
    const int*   src  = (const int*)d_in[2];
    const int*   dst  = (const int*)d_in[3];
    const float* Wm1  = (const float*)d_in[4];
    const float* bm1  = (const float*)d_in[5];
    const float* Wu1  = (const float*)d_in[6];
    const float* bu1  = (const float*)d_in[7];
    const float* Wm2  = (const float*)d_in[8];
    const float* bm2  = (const float*)d_in[9];
    const float* Wu2  = (const float*)d_in[10];
    const float* bu2  = (const float*)d_in[11];
    const float* Wo   = (const float*)d_in[12];
    const float* bo   = (const float*)d_in[13];
    float* out = (float*)d_out;

    const int N = in_sizes[0] / DD;
    const int E = in_sizes[2];

    // ws layout
    char* p = (char*)d_ws;
    float* h1     = (float*)p; p += (size_t)N * DD * 4;
    float* h2     = (float*)p; p += (size_t)N * DD * 4;
    float* hm     = (float*)p; p += (size_t)N * DD * 4;
    float* pooled = (float*)p; p += (size_t)N * DD * 4;
    int*   deg    = (int*)p;   p += (size_t)N * 4;
    int*   off    = (int*)p;   p += (size_t)(N + 1) * 4;
    int*   cursor = (int*)p;   p += (size_t)N * 4;
    int*   eidx   = (int*)p;   p += (size_t)E * 4;
    size_t needed = (size_t)(p - (char*)d_ws);

    dim3 blk(256);
    int nbN = (N + 255) / 256;
    int nbE = (E + 255) / 256;

    if (ws_size >= needed) {
        // ---- CSR build (stateless: rebuilt every call) ----
        hipMemsetAsync(deg, 0, (size_t)N * 4, stream);
        count_deg<<<nbE, blk, 0, stream>>>(dst, deg, E);
        scan_kernel<<<1, 1024, 0, stream>>>(deg, off, cursor, N);
        fill_eidx<<<nbE, blk, 0, stream>>>(dst, cursor, eidx, E);

        // ---- layer 1 ----
        node_transform<<<nbN, blk, 0, stream>>>(node, Wm1, bm1, hm, pooled, N);
        fused_edge_gather<<<nbE, blk, 0, stream>>>(ef, hm, src, dst, off, eidx,
                                                   Wm1 + DD * DD, pooled, E, N);
        update_kernel<<<nbN, blk, 0, stream>>>(node, pooled, Wu1, bu1, h1, N);

        // ---- layer 2 ----
        node_transform<<<nbN, blk, 0, stream>>>(h1, Wm2, bm2, hm, pooled, N);
        fused_edge_gather<<<nbE, blk, 0, stream>>>(ef, hm, src, dst, off, eidx,
                                                   Wm2 + DD * DD, pooled, E, N);
        update_kernel<<<nbN, blk, 0, stream>>>(h1, pooled, Wu2, bu2, h2, N);
    } else {
        // ---- fallback: atomic scatter path ----
        node_transform<<<nbN, blk, 0, stream>>>(node, Wm1, bm1, hm, pooled, N);
        edge_kernel_atomic<<<nbE, blk, 0, stream>>>(ef, hm, src, dst, Wm1 + DD * DD, pooled, E);
        update_kernel<<<nbN, blk, 0, stream>>>(node, pooled, Wu1, bu1, h1, N);

        node_transform<<<nbN, blk, 0, stream>>>(h1, Wm2, bm2, hm, pooled, N);
        edge_kernel_atomic<<<nbE, blk, 0, stream>>>(ef, hm, src, dst, Wm2 + DD * DD, pooled, E);
        update_kernel<<<nbN, blk, 0, stream>>>(h1, pooled, Wu2, bu2, h2, N);
    }

    // ---- readout ----
    out_kernel<<<nbN, blk, 0, stream>>>(h2, Wo, bo, out, N);
}

// Round 4
// 900.047 us; speedup vs baseline: 1.6074x; 1.6074x over previous
//
#include <hip/hip_runtime.h>

#define DD 64

__device__ __forceinline__ float fast_tanh(float x) {
    float e = __builtin_amdgcn_exp2f(x * 2.885390081777927f); // 2x * log2(e)
    return 1.0f - 2.0f * __builtin_amdgcn_rcpf(e + 1.0f);
}

// ---------------- CSR build ----------------

__global__ void __launch_bounds__(256) count_deg(
    const int* __restrict__ dst, int* __restrict__ deg, int E)
{
    int e = blockIdx.x * 256 + threadIdx.x;
    if (e < E) atomicAdd(&deg[dst[e]], 1);
}

// single block, 1024 threads: exclusive scan deg[N] -> off[N+1], cursor = off
__global__ void __launch_bounds__(1024) scan_kernel(
    const int* __restrict__ deg, int* __restrict__ off,
    int* __restrict__ cursor, int N)
{
    __shared__ int part[1024];
    int t = threadIdx.x;
    int per = (N + 1023) / 1024;
    int lo = t * per;
    int hi = lo + per; if (hi > N) hi = N;
    int s = 0;
    for (int i = lo; i < hi; ++i) s += deg[i];
    part[t] = s;
    __syncthreads();
    for (int d = 1; d < 1024; d <<= 1) {
        int v = 0;
        if (t >= d) v = part[t - d];
        __syncthreads();
        if (t >= d) part[t] += v;
        __syncthreads();
    }
    int run = (t == 0) ? 0 : part[t - 1];
    for (int i = lo; i < hi; ++i) {
        off[i] = run; cursor[i] = run;
        run += deg[i];
    }
    if (lo < N && hi == N) off[N] = run;
}

__global__ void __launch_bounds__(256) fill_eidx(
    const int* __restrict__ dst, int* __restrict__ cursor,
    int* __restrict__ eidx, int E)
{
    int e = blockIdx.x * 256 + threadIdx.x;
    if (e < E) {
        int slot = atomicAdd(&cursor[dst[e]], 1);
        eidx[slot] = e;
    }
}

// ---------------- compute kernels ----------------

// hm = h @ W(top 64x64) + b ; zero pooled (atomics accumulate into it)
__global__ void __launch_bounds__(256) node_transform(
    const float* __restrict__ h, const float* __restrict__ W,
    const float* __restrict__ b, float* __restrict__ hm,
    float* __restrict__ pooled, int N)
{
    int n = blockIdx.x * 256 + threadIdx.x;
    if (n >= N) return;
    float acc[DD];
    #pragma unroll
    for (int j = 0; j < DD; ++j) acc[j] = b[j];
    const float4* hrow = reinterpret_cast<const float4*>(h + (size_t)n * DD);
    #pragma unroll 1
    for (int kk = 0; kk < DD / 4; ++kk) {
        float4 a = hrow[kk];
        const float* Wr = W + kk * 4 * DD;   // uniform -> s_load
        #pragma unroll
        for (int j = 0; j < DD; ++j)
            acc[j] += a.x * Wr[j] + a.y * Wr[DD + j]
                    + a.z * Wr[2 * DD + j] + a.w * Wr[3 * DD + j];
    }
    float4* orow = reinterpret_cast<float4*>(hm + (size_t)n * DD);
    float4* prow = reinterpret_cast<float4*>(pooled + (size_t)n * DD);
    #pragma unroll
    for (int jj = 0; jj < DD / 4; ++jj) {
        orow[jj] = make_float4(acc[4*jj], acc[4*jj+1], acc[4*jj+2], acc[4*jj+3]);
        prow[jj] = make_float4(0.f, 0.f, 0.f, 0.f);
    }
}

// Fused: per CSR slot compute msg = tanh(ef[e]@W + hm[src]); store msg to the
// thread's OWN LDS row (XOR-swizzled, conflict-free, no atomics); then
// segment-sum by READING LDS: wave-per-node, lane = channel.
__global__ void __launch_bounds__(256) fused_edge_gather(
    const float* __restrict__ ef, const float* __restrict__ hm,
    const int* __restrict__ src, const int* __restrict__ dst,
    const int* __restrict__ off, const int* __restrict__ eidx,
    const float* __restrict__ W, float* __restrict__ pooled,
    int E, int N)
{
    __shared__ float tile[256 * DD];   // 64 KiB; float4 slot k stored at k^(row&15)
    int t  = threadIdx.x;
    int s0 = blockIdx.x * 256;
    int s1 = s0 + 256; if (s1 > E) s1 = E;

    // ---- phase 1: per-slot message into own LDS row ----
    int slot = s0 + t;
    if (slot < s1) {
        int e = eidx[slot];
        int s = src[e];
        const float4* erow = reinterpret_cast<const float4*>(ef + (size_t)e * DD);
        const float4* hrow = reinterpret_cast<const float4*>(hm + (size_t)s * DD);
        float4 a[16];
        #pragma unroll
        for (int kk = 0; kk < 16; ++kk) a[kk] = erow[kk];   // 16 loads in flight
        float acc[DD];
        #pragma unroll
        for (int j = 0; j < DD; ++j) acc[j] = 0.0f;
        #pragma unroll 1
        for (int kk = 0; kk < 16; ++kk) {
            float4 aa = a[kk];
            const float* Wr = W + kk * 4 * DD;   // uniform -> s_load broadcast
            #pragma unroll
            for (int j = 0; j < DD; ++j)
                acc[j] += aa.x * Wr[j] + aa.y * Wr[DD + j]
                        + aa.z * Wr[2 * DD + j] + aa.w * Wr[3 * DD + j];
        }
        #pragma unroll
        for (int jj = 0; jj < 16; ++jj) {
            float4 hv = hrow[jj];
            float4 m;
            m.x = fast_tanh(acc[4*jj+0] + hv.x);
            m.y = fast_tanh(acc[4*jj+1] + hv.y);
            m.z = fast_tanh(acc[4*jj+2] + hv.z);
            m.w = fast_tanh(acc[4*jj+3] + hv.w);
            int sl = (jj ^ (t & 15)) << 2;       // XOR swizzle: spread quads
            *reinterpret_cast<float4*>(&tile[t * DD + sl]) = m;
        }
    }
    __syncthreads();

    // ---- phase 2: segment-sum from LDS; wave per node, lane = channel ----
    int d_first = dst[eidx[s0]];                 // uniform -> broadcast
    int d_last  = dst[eidx[s1 - 1]];
    int ch = t & 63;
    int c4 = ch >> 2, ce = ch & 3;
    for (int n = d_first + (t >> 6); n <= d_last; n += 4) {
        int lo = off[n], hi = off[n + 1];
        int clo = lo > s0 ? lo : s0;
        int chi = hi < s1 ? hi : s1;
        if (clo >= chi) continue;                // node untouched by this block
        float v = 0.0f;
        for (int s = clo; s < chi; ++s) {
            int r = s - s0;
            v += tile[r * DD + ((c4 ^ (r & 15)) << 2) + ce];
        }
        if (lo >= s0 && hi <= s1)
            pooled[(size_t)n * DD + ch] = v;     // exclusively owned -> store
        else
            atomicAdd(pooled + (size_t)n * DD + ch, v);  // straddles blocks
    }
}

// fallback path: atomic scatter if ws too small
__global__ void __launch_bounds__(256) edge_kernel_atomic(
    const float* __restrict__ ef, const float* __restrict__ hm,
    const int* __restrict__ src, const int* __restrict__ dst,
    const float* __restrict__ W, float* __restrict__ pooled, int E)
{
    int e = blockIdx.x * 256 + threadIdx.x;
    if (e >= E) return;
    int s = src[e];
    int d = dst[e];
    float acc[DD];
    #pragma unroll
    for (int j = 0; j < DD; ++j) acc[j] = 0.0f;
    const float4* erow = reinterpret_cast<const float4*>(ef + (size_t)e * DD);
    #pragma unroll 1
    for (int kk = 0; kk < DD / 4; ++kk) {
        float4 a = erow[kk];
        const float* Wr = W + kk * 4 * DD;
        #pragma unroll
        for (int j = 0; j < DD; ++j)
            acc[j] += a.x * Wr[j] + a.y * Wr[DD + j]
                    + a.z * Wr[2 * DD + j] + a.w * Wr[3 * DD + j];
    }
    const float4* hrow = reinterpret_cast<const float4*>(hm + (size_t)s * DD);
    float* prow = pooled + (size_t)d * DD;
    #pragma unroll
    for (int jj = 0; jj < DD / 4; ++jj) {
        float4 hv = hrow[jj];
        atomicAdd(prow + 4*jj + 0, fast_tanh(acc[4*jj+0] + hv.x));
        atomicAdd(prow + 4*jj + 1, fast_tanh(acc[4*jj+1] + hv.y));
        atomicAdd(prow + 4*jj + 2, fast_tanh(acc[4*jj+2] + hv.z));
        atomicAdd(prow + 4*jj + 3, fast_tanh(acc[4*jj+3] + hv.w));
    }
}

// h_new = tanh(h @ Wu[0:64] + pooled @ Wu[64:128] + bu)
__global__ void __launch_bounds__(256) update_kernel(
    const float* __restrict__ h, const float* __restrict__ pooled,
    const float* __restrict__ Wu, const float* __restrict__ bu,
    float* __restrict__ hout, int N)
{
    int n = blockIdx.x * 256 + threadIdx.x;
    if (n >= N) return;
    float acc[DD];
    #pragma unroll
    for (int j = 0; j < DD; ++j) acc[j] = bu[j];
    const float4* hrow = reinterpret_cast<const float4*>(h + (size_t)n * DD);
    #pragma unroll 1
    for (int kk = 0; kk < DD / 4; ++kk) {
        float4 a = hrow[kk];
        const float* Wr = Wu + kk * 4 * DD;
        #pragma unroll
        for (int j = 0; j < DD; ++j)
            acc[j] += a.x * Wr[j] + a.y * Wr[DD + j]
                    + a.z * Wr[2 * DD + j] + a.w * Wr[3 * DD + j];
    }
    const float4* prow = reinterpret_cast<const float4*>(pooled + (size_t)n * DD);
    #pragma unroll 1
    for (int kk = 0; kk < DD / 4; ++kk) {
        float4 a = prow[kk];
        const float* Wr = Wu + (DD + kk * 4) * DD;
        #pragma unroll
        for (int j = 0; j < DD; ++j)
            acc[j] += a.x * Wr[j] + a.y * Wr[DD + j]
                    + a.z * Wr[2 * DD + j] + a.w * Wr[3 * DD + j];
    }
    float4* orow = reinterpret_cast<float4*>(hout + (size_t)n * DD);
    #pragma unroll
    for (int jj = 0; jj < DD / 4; ++jj)
        orow[jj] = make_float4(fast_tanh(acc[4*jj]),   fast_tanh(acc[4*jj+1]),
                               fast_tanh(acc[4*jj+2]), fast_tanh(acc[4*jj+3]));
}

__global__ void __launch_bounds__(256) out_kernel(
    const float* __restrict__ h, const float* __restrict__ Wo,
    const float* __restrict__ bo, float* __restrict__ out, int N)
{
    int n = blockIdx.x * 256 + threadIdx.x;
    if (n >= N) return;
    const float4* hrow = reinterpret_cast<const float4*>(h + (size_t)n * DD);
    float acc = bo[0];
    #pragma unroll
    for (int kk = 0; kk < DD / 4; ++kk) {
        float4 a = hrow[kk];
        acc += a.x * Wo[4*kk] + a.y * Wo[4*kk+1] + a.z * Wo[4*kk+2] + a.w * Wo[4*kk+3];
    }
    out[n] = acc;
}

extern "C" void kernel_launch(void* const* d_in, const int* in_sizes, int n_in,
                              void* d_out, int out_size, void* d_ws, size_t ws_size,
                              hipStream_t stream) {
    const float* node = (const float*)d_in[0];
    const float* ef   = (const float*)d_in[1];
    const int*   src  = (const int*)d_in[2];
    const int*   dst  = (const int*)d_in[3];
    const float* Wm1  = (const float*)d_in[4];
    const float* bm1  = (const float*)d_in[5];
    const float* Wu1  = (const float*)d_in[6];
    const float* bu1  = (const float*)d_in[7];
    const float* Wm2  = (const float*)d_in[8];
    const float* bm2  = (const float*)d_in[9];
    const float* Wu2  = (const float*)d_in[10];
    const float* bu2  = (const float*)d_in[11];
    const float* Wo   = (const float*)d_in[12];
    const float* bo   = (const float*)d_in[13];
    float* out = (float*)d_out;

    const int N = in_sizes[0] / DD;
    const int E = in_sizes[2];

    // ws layout
    char* p = (char*)d_ws;
    float* h1     = (float*)p; p += (size_t)N * DD * 4;
    float* h2     = (float*)p; p += (size_t)N * DD * 4;
    float* hm     = (float*)p; p += (size_t)N * DD * 4;
    float* pooled = (float*)p; p += (size_t)N * DD * 4;
    int*   deg    = (int*)p;   p += (size_t)N * 4;
    int*   off    = (int*)p;   p += (size_t)(N + 1) * 4;
    int*   cursor = (int*)p;   p += (size_t)N * 4;
    int*   eidx   = (int*)p;   p += (size_t)E * 4;
    size_t needed = (size_t)(p - (char*)d_ws);

    dim3 blk(256);
    int nbN = (N + 255) / 256;
    int nbE = (E + 255) / 256;

    if (ws_size >= needed) {
        // ---- CSR build (stateless: rebuilt every call) ----
        hipMemsetAsync(deg, 0, (size_t)N * 4, stream);
        count_deg<<<nbE, blk, 0, stream>>>(dst, deg, E);
        scan_kernel<<<1, 1024, 0, stream>>>(deg, off, cursor, N);
        fill_eidx<<<nbE, blk, 0, stream>>>(dst, cursor, eidx, E);

        // ---- layer 1 ----
        node_transform<<<nbN, blk, 0, stream>>>(node, Wm1, bm1, hm, pooled, N);
        fused_edge_gather<<<nbE, blk, 0, stream>>>(ef, hm, src, dst, off, eidx,
                                                   Wm1 + DD * DD, pooled, E, N);
        update_kernel<<<nbN, blk, 0, stream>>>(node, pooled, Wu1, bu1, h1, N);

        // ---- layer 2 ----
        node_transform<<<nbN, blk, 0, stream>>>(h1, Wm2, bm2, hm, pooled, N);
        fused_edge_gather<<<nbE, blk, 0, stream>>>(ef, hm, src, dst, off, eidx,
                                                   Wm2 + DD * DD, pooled, E, N);
        update_kernel<<<nbN, blk, 0, stream>>>(h1, pooled, Wu2, bu2, h2, N);
    } else {
        // ---- fallback: atomic scatter path ----
        node_transform<<<nbN, blk, 0, stream>>>(node, Wm1, bm1, hm, pooled, N);
        edge_kernel_atomic<<<nbE, blk, 0, stream>>>(ef, hm, src, dst, Wm1 + DD * DD, pooled, E);
        update_kernel<<<nbN, blk, 0, stream>>>(node, pooled, Wu1, bu1, h1, N);

        node_transform<<<nbN, blk, 0, stream>>>(h1, Wm2, bm2, hm, pooled, N);
        edge_kernel_atomic<<<nbE, blk, 0, stream>>>(ef, hm, src, dst, Wm2 + DD * DD, pooled, E);
        update_kernel<<<nbN, blk, 0, stream>>>(h1, pooled, Wu2, bu2, h2, N);
    }

    // ---- readout ----
    out_kernel<<<nbN, blk, 0, stream>>>(h2, Wo, bo, out, N);
}